// Round 6
// baseline (395.836 us; speedup 1.0000x reference)
//
#include <hip/hip_runtime.h>
#include <hip/hip_fp16.h>
#include <stdint.h>

#define NNODES 50000
#define NEDGES 800000
#define NHID 96
#define NCLS 16
#define NB ((NNODES + 255) / 256)   // 196 scan blocks

// graph-build histogram config: 64 blocks, 12500 edges each; node space split
// into two halves of 25000; LDS histogram = 12500 u32 words (u16 pair-packed).
#define BBLK 64
#define EPB (NEDGES / BBLK)         // 12500
#define HWORDS 12500

// ---------- JAX Threefry-2x32 (Random123 20-round, matches jax._src.prng) ----------
__host__ __device__ inline void tf2x32(uint32_t k0, uint32_t k1, uint32_t x0, uint32_t x1,
                                       uint32_t& o0, uint32_t& o1) {
  uint32_t k2 = k0 ^ k1 ^ 0x1BD11BDAu;
#define TFROT(v, r) (((v) << (r)) | ((v) >> (32 - (r))))
#define TFR(r) { x0 += x1; x1 = TFROT(x1, r); x1 ^= x0; }
  x0 += k0; x1 += k1;
  TFR(13) TFR(15) TFR(26) TFR(6)
  x0 += k1; x1 += k2 + 1u;
  TFR(17) TFR(29) TFR(16) TFR(24)
  x0 += k2; x1 += k0 + 2u;
  TFR(13) TFR(15) TFR(26) TFR(6)
  x0 += k0; x1 += k1 + 3u;
  TFR(17) TFR(29) TFR(16) TFR(24)
  x0 += k1; x1 += k2 + 4u;
  TFR(13) TFR(15) TFR(26) TFR(6)
  x0 += k2; x1 += k0 + 5u;
  o0 = x0; o1 = x1;
#undef TFR
#undef TFROT
}

__device__ inline bool keep_bit(uint32_t k0, uint32_t k1, uint32_t j) {
  uint32_t o0, o1;
  tf2x32(k0, k1, 0u, j, o0, o1);
  return (((o0 ^ o1) >> 31) == 0u);   // uniform<0.5 <=> MSB==0
}

// ---------- pass 1: per-block LDS histograms of dst (ideg) and src (odeg) ----------
// slabI/slabO layout: [b][25000 words]; global word g = n>>1 covers nodes 2g (lo16), 2g+1 (hi16).
__global__ __launch_bounds__(256) void hist_kernel(
    const int* __restrict__ src, const int* __restrict__ dst,
    uint32_t* __restrict__ slabI, uint32_t* __restrict__ slabO) {
  __shared__ uint32_t H[HWORDS];
  const int tid = threadIdx.x, b = blockIdx.x;
  const int e0 = b * EPB, e1 = e0 + EPB;
  for (int a = 0; a < 2; ++a) {
    const int* arr = (a == 0) ? dst : src;
    uint32_t* slab = (a == 0) ? slabI : slabO;
    for (int h = 0; h < 2; ++h) {
      for (int w = tid; w < HWORDS; w += 256) H[w] = 0;
      __syncthreads();
      for (int e = e0 + tid; e < e1; e += 256) {
        int ln = arr[e] - h * 25000;
        if ((unsigned)ln < 25000u)
          atomicAdd(&H[ln >> 1], 1u << ((ln & 1) * 16));
      }
      __syncthreads();
      uint32_t* dp = slab + (size_t)b * 25000 + h * HWORDS;
      for (int w = tid; w < HWORDS; w += 256) dp[w] = H[w];
      __syncthreads();
    }
  }
}

// ---------- sum slabs -> ideg / odeg ----------
__global__ __launch_bounds__(256) void reduce_kernel(
    const uint32_t* __restrict__ slabI, const uint32_t* __restrict__ slabO,
    int* __restrict__ ideg, int* __restrict__ odeg) {
  int g = blockIdx.x * 256 + threadIdx.x;
  if (g >= NNODES / 2) return;
  uint32_t li = 0, hi = 0, lo = 0, ho = 0;
  for (int b = 0; b < BBLK; ++b) {
    uint32_t vi = slabI[(size_t)b * 25000 + g];
    uint32_t vo = slabO[(size_t)b * 25000 + g];
    li += vi & 0xFFFFu; hi += vi >> 16;
    lo += vo & 0xFFFFu; ho += vo >> 16;
  }
  ideg[2 * g] = (int)li; ideg[2 * g + 1] = (int)hi;
  odeg[2 * g] = (int)lo; odeg[2 * g + 1] = (int)ho;
}

// ---------- hierarchical exclusive scan of ideg -> row_ptr ----------
__global__ __launch_bounds__(256) void scan_blocks_kernel(
    const int* __restrict__ ideg, int* __restrict__ bsum) {
  __shared__ int lds[256];
  const int tid = threadIdx.x;
  int i = blockIdx.x * 256 + tid;
  lds[tid] = (i < NNODES) ? ideg[i] : 0;
  __syncthreads();
  for (int off = 128; off > 0; off >>= 1) {
    if (tid < off) lds[tid] += lds[tid + off];
    __syncthreads();
  }
  if (tid == 0) bsum[blockIdx.x] = lds[0];
}

__global__ __launch_bounds__(256) void scan_top_kernel(
    const int* __restrict__ bsum, int* __restrict__ boff) {
  __shared__ int lds[256];
  const int tid = threadIdx.x;
  int v = (tid < NB) ? bsum[tid] : 0;
  lds[tid] = v;
  __syncthreads();
  for (int off = 1; off < 256; off <<= 1) {
    int t = (tid >= off) ? lds[tid - off] : 0;
    __syncthreads();
    lds[tid] += t;
    __syncthreads();
  }
  if (tid < NB) boff[tid] = lds[tid] - v;   // exclusive
}

__global__ __launch_bounds__(256) void scan_write_kernel(
    const int* __restrict__ ideg, const int* __restrict__ boff,
    int* __restrict__ row_ptr) {
  __shared__ int lds[256];
  const int tid = threadIdx.x;
  int i = blockIdx.x * 256 + tid;
  int v = (i < NNODES) ? ideg[i] : 0;
  lds[tid] = v;
  __syncthreads();
  for (int off = 1; off < 256; off <<= 1) {
    int t = (tid >= off) ? lds[tid - off] : 0;
    __syncthreads();
    lds[tid] += t;
    __syncthreads();
  }
  if (i < NNODES) row_ptr[i] = boff[blockIdx.x] + lds[tid] - v;
  if (i == 0) row_ptr[NNODES] = NEDGES;
}

__global__ __launch_bounds__(256) void inv_kernel(
    const int* __restrict__ odeg, const int* __restrict__ ideg,
    float* __restrict__ inv_o, float* __restrict__ inv_i) {
  int n = blockIdx.x * 256 + threadIdx.x;
  if (n >= NNODES) return;
  inv_o[n] = rsqrtf(fmaxf((float)odeg[n], 1.0f));
  inv_i[n] = rsqrtf(fmaxf((float)ideg[n], 1.0f));
}

// ---------- per-(block,node) CSR base offsets ----------
__global__ __launch_bounds__(256) void base_kernel(
    const uint32_t* __restrict__ slabI, const int* __restrict__ row_ptr,
    int* __restrict__ baseSlab) {
  int g = blockIdx.x * 256 + threadIdx.x;
  if (g >= NNODES / 2) return;
  int runL = row_ptr[2 * g], runH = row_ptr[2 * g + 1];
  for (int b = 0; b < BBLK; ++b) {
    uint32_t v = slabI[(size_t)b * 25000 + g];
    baseSlab[(size_t)b * NNODES + 2 * g]     = runL;
    baseSlab[(size_t)b * NNODES + 2 * g + 1] = runH;
    runL += (int)(v & 0xFFFFu);
    runH += (int)(v >> 16);
  }
}

// ---------- pass 2: atomic-free CSR fill via LDS-histogram replay ----------
// packed weight w' = ew * 2 * inv_o[src]  (dropout 1/(1-p) and D_out^-1/2 folded in)
__global__ __launch_bounds__(256) void fillh_kernel(
    const int* __restrict__ src, const int* __restrict__ dst, const float* __restrict__ ew,
    const int* __restrict__ baseSlab, const float* __restrict__ inv_o,
    uint32_t* __restrict__ csr) {
  __shared__ uint32_t H[HWORDS];
  const int tid = threadIdx.x, b = blockIdx.x;
  const int e0 = b * EPB, e1 = e0 + EPB;
  const int* bs = baseSlab + (size_t)b * NNODES;
  for (int h = 0; h < 2; ++h) {
    for (int w = tid; w < HWORDS; w += 256) H[w] = 0;
    __syncthreads();
    for (int e = e0 + tid; e < e1; e += 256) {
      int d = dst[e];
      int ln = d - h * 25000;
      if ((unsigned)ln < 25000u) {
        int sh = (ln & 1) * 16;
        uint32_t old = atomicAdd(&H[ln >> 1], 1u << sh);
        int rank = (int)((old >> sh) & 0xFFFFu);
        int pos = bs[d] + rank;
        int s = src[e];
        float wp = ew[e] * 2.0f * inv_o[s];
        csr[pos] = ((uint32_t)s << 16) | (uint32_t)__half_as_ushort(__float2half_rn(wp));
      }
    }
    __syncthreads();
  }
}

// ---------- layer-0 dropout: pure mask (scale folded into CSR weight) ----------
__global__ __launch_bounds__(256) void drop0_kernel(
    const float* __restrict__ h, float* __restrict__ X, uint32_t k0, uint32_t k1) {
  int j = blockIdx.x * 256 + threadIdx.x;
  if (j >= NNODES * NHID) return;
  X[j] = keep_bit(k0, k1, (uint32_t)j) ? h[j] : 0.0f;
}

// ---------- GEMM96: Yh[N,96](fp16) = X[N,96](fp32) @ W[96,96], LDS-staged W ----------
__global__ __launch_bounds__(256) void gemm96_kernel(
    const float* __restrict__ X, const float* __restrict__ W, __half* __restrict__ Yh) {
  __shared__ float Wl[96 * 96];
  const int tid = threadIdx.x;
  {
    const float4* Wg = (const float4*)W;
    float4* Ws = (float4*)Wl;
#pragma unroll
    for (int i = 0; i < 9; ++i)
      Ws[tid + i * 256] = Wg[tid + i * 256];
  }
  __syncthreads();

  const int cg = tid & 7;
  const int rq = tid >> 3;
  const int row0 = blockIdx.x * 128 + rq * 4;
  const int c0 = cg * 12;

  float acc[4][12];
#pragma unroll
  for (int r = 0; r < 4; ++r)
#pragma unroll
    for (int c = 0; c < 12; ++c) acc[r][c] = 0.f;

  const float* xr[4];
#pragma unroll
  for (int r = 0; r < 4; ++r) {
    int rr = row0 + r; if (rr > NNODES - 1) rr = NNODES - 1;
    xr[r] = X + (size_t)rr * 96;
  }

  for (int k = 0; k < 96; k += 4) {
    float4 x4[4];
#pragma unroll
    for (int r = 0; r < 4; ++r) x4[r] = *(const float4*)(xr[r] + k);
#pragma unroll
    for (int kk = 0; kk < 4; ++kk) {
      const float4* wp = (const float4*)(Wl + (k + kk) * 96 + c0);
      float4 w0 = wp[0], w1 = wp[1], w2 = wp[2];
      float xv[4] = { (&x4[0].x)[kk], (&x4[1].x)[kk], (&x4[2].x)[kk], (&x4[3].x)[kk] };
#pragma unroll
      for (int r = 0; r < 4; ++r) {
        acc[r][0]  += xv[r] * w0.x; acc[r][1]  += xv[r] * w0.y;
        acc[r][2]  += xv[r] * w0.z; acc[r][3]  += xv[r] * w0.w;
        acc[r][4]  += xv[r] * w1.x; acc[r][5]  += xv[r] * w1.y;
        acc[r][6]  += xv[r] * w1.z; acc[r][7]  += xv[r] * w1.w;
        acc[r][8]  += xv[r] * w2.x; acc[r][9]  += xv[r] * w2.y;
        acc[r][10] += xv[r] * w2.z; acc[r][11] += xv[r] * w2.w;
      }
    }
  }

#pragma unroll
  for (int r = 0; r < 4; ++r) {
    int rr = row0 + r;
    if (rr < NNODES) {
      __half2* hp = (__half2*)(Yh + (size_t)rr * 96 + c0);
#pragma unroll
      for (int c = 0; c < 6; ++c)
        hp[c] = __floats2half2_rn(acc[r][2 * c], acc[r][2 * c + 1]);
    }
  }
}

// ---------- GEMM16: Y2h[N,16](fp16) = X[N,96] @ W[96,16], LDS-staged W ----------
__global__ __launch_bounds__(256) void gemm16_kernel(
    const float* __restrict__ X, const float* __restrict__ W, __half* __restrict__ Y2h) {
  __shared__ float Wl[96 * 16];
  const int tid = threadIdx.x;
  {
    const float4* Wg = (const float4*)W;
    float4* Ws = (float4*)Wl;
    for (int i = tid; i < 384; i += 256) Ws[i] = Wg[i];
  }
  __syncthreads();

  const int row0 = blockIdx.x * 512 + tid * 2;
  const float* xr[2];
#pragma unroll
  for (int r = 0; r < 2; ++r) {
    int rr = row0 + r; if (rr > NNODES - 1) rr = NNODES - 1;
    xr[r] = X + (size_t)rr * 96;
  }

  float acc[2][16];
#pragma unroll
  for (int r = 0; r < 2; ++r)
#pragma unroll
    for (int c = 0; c < 16; ++c) acc[r][c] = 0.f;

  for (int k = 0; k < 96; k += 4) {
    float4 x4[2];
#pragma unroll
    for (int r = 0; r < 2; ++r) x4[r] = *(const float4*)(xr[r] + k);
#pragma unroll
    for (int kk = 0; kk < 4; ++kk) {
      const float4* wp = (const float4*)(Wl + (k + kk) * 16);
      float4 w0 = wp[0], w1 = wp[1], w2 = wp[2], w3 = wp[3];
#pragma unroll
      for (int r = 0; r < 2; ++r) {
        float xv = (&x4[r].x)[kk];
        acc[r][0]  += xv * w0.x; acc[r][1]  += xv * w0.y;
        acc[r][2]  += xv * w0.z; acc[r][3]  += xv * w0.w;
        acc[r][4]  += xv * w1.x; acc[r][5]  += xv * w1.y;
        acc[r][6]  += xv * w1.z; acc[r][7]  += xv * w1.w;
        acc[r][8]  += xv * w2.x; acc[r][9]  += xv * w2.y;
        acc[r][10] += xv * w2.z; acc[r][11] += xv * w2.w;
        acc[r][12] += xv * w3.x; acc[r][13] += xv * w3.y;
        acc[r][14] += xv * w3.z; acc[r][15] += xv * w3.w;
      }
    }
  }

#pragma unroll
  for (int r = 0; r < 2; ++r) {
    int rr = row0 + r;
    if (rr < NNODES) {
      __half2* hp = (__half2*)(Y2h + (size_t)rr * 16);
#pragma unroll
      for (int c = 0; c < 8; ++c)
        hp[c] = __floats2half2_rn(acc[r][2 * c], acc[r][2 * c + 1]);
    }
  }
}

// ---------- CSR gather (fp16 Y) + inv_in*bias + ReLU + next-layer dropout mask ----------
__global__ __launch_bounds__(256) void gather96_drop_kernel(
    const __half* __restrict__ Yh, const uint32_t* __restrict__ csr,
    const int* __restrict__ row_ptr, const float* __restrict__ inv_in,
    const float* __restrict__ bias, float* __restrict__ Xn,
    uint32_t k0, uint32_t k1) {
  int tid = blockIdx.x * 256 + threadIdx.x;
  int n = tid / 12;
  int q = tid - n * 12;        // 8-dim chunk within the 96-dim row
  if (n >= NNODES) return;
  int beg = row_ptr[n], end = row_ptr[n + 1];
  float acc[8];
#pragma unroll
  for (int i = 0; i < 8; ++i) acc[i] = 0.f;
  for (int p = beg; p < end; ++p) {
    uint32_t pr = csr[p];
    int s = pr >> 16;
    float w = __half2float(__ushort_as_half((unsigned short)(pr & 0xFFFFu)));
    uint4 u = *(const uint4*)(Yh + (size_t)s * 96 + q * 8);
    float2 f0 = __half22float2(*(__half2*)&u.x);
    float2 f1 = __half22float2(*(__half2*)&u.y);
    float2 f2 = __half22float2(*(__half2*)&u.z);
    float2 f3 = __half22float2(*(__half2*)&u.w);
    acc[0] += f0.x * w; acc[1] += f0.y * w;
    acc[2] += f1.x * w; acc[3] += f1.y * w;
    acc[4] += f2.x * w; acc[5] += f2.y * w;
    acc[6] += f3.x * w; acc[7] += f3.y * w;
  }
  float iv = inv_in[n];
  float4 b0 = *(const float4*)(bias + q * 8);
  float4 b1 = *(const float4*)(bias + q * 8 + 4);
  float o[8];
  o[0] = fmaxf(acc[0] * iv + b0.x, 0.f);
  o[1] = fmaxf(acc[1] * iv + b0.y, 0.f);
  o[2] = fmaxf(acc[2] * iv + b0.z, 0.f);
  o[3] = fmaxf(acc[3] * iv + b0.w, 0.f);
  o[4] = fmaxf(acc[4] * iv + b1.x, 0.f);
  o[5] = fmaxf(acc[5] * iv + b1.y, 0.f);
  o[6] = fmaxf(acc[6] * iv + b1.z, 0.f);
  o[7] = fmaxf(acc[7] * iv + b1.w, 0.f);
  uint32_t jb = (uint32_t)(n * 96 + q * 8);
#pragma unroll
  for (int i = 0; i < 8; ++i)
    o[i] = keep_bit(k0, k1, jb + i) ? o[i] : 0.f;
  float* xp = Xn + (size_t)n * 96 + q * 8;
  *(float4*)(xp + 0) = make_float4(o[0], o[1], o[2], o[3]);
  *(float4*)(xp + 4) = make_float4(o[4], o[5], o[6], o[7]);
}

// ---------- layer 2: CSR gather (fp16 Y2) + bias + log_softmax ----------
__global__ __launch_bounds__(256) void gather16_lsm_kernel(
    const __half* __restrict__ Y2h, const uint32_t* __restrict__ csr,
    const int* __restrict__ row_ptr, const float* __restrict__ inv_in,
    const float* __restrict__ b2, float* __restrict__ out) {
  int n = blockIdx.x * 256 + threadIdx.x;
  if (n >= NNODES) return;
  int beg = row_ptr[n], end = row_ptr[n + 1];
  float acc[16];
#pragma unroll
  for (int i = 0; i < 16; ++i) acc[i] = 0.f;
  for (int p = beg; p < end; ++p) {
    uint32_t pr = csr[p];
    int s = pr >> 16;
    float w = __half2float(__ushort_as_half((unsigned short)(pr & 0xFFFFu)));
    const uint4* yp = (const uint4*)(Y2h + (size_t)s * 16);
    uint4 ua = yp[0], ub = yp[1];
    float2 f0 = __half22float2(*(__half2*)&ua.x);
    float2 f1 = __half22float2(*(__half2*)&ua.y);
    float2 f2 = __half22float2(*(__half2*)&ua.z);
    float2 f3 = __half22float2(*(__half2*)&ua.w);
    float2 f4 = __half22float2(*(__half2*)&ub.x);
    float2 f5 = __half22float2(*(__half2*)&ub.y);
    float2 f6 = __half22float2(*(__half2*)&ub.z);
    float2 f7 = __half22float2(*(__half2*)&ub.w);
    acc[0]  += f0.x * w; acc[1]  += f0.y * w;
    acc[2]  += f1.x * w; acc[3]  += f1.y * w;
    acc[4]  += f2.x * w; acc[5]  += f2.y * w;
    acc[6]  += f3.x * w; acc[7]  += f3.y * w;
    acc[8]  += f4.x * w; acc[9]  += f4.y * w;
    acc[10] += f5.x * w; acc[11] += f5.y * w;
    acc[12] += f6.x * w; acc[13] += f6.y * w;
    acc[14] += f7.x * w; acc[15] += f7.y * w;
  }
  float iv = inv_in[n];
  float v[16];
#pragma unroll
  for (int i = 0; i < 16; ++i) v[i] = acc[i] * iv + b2[i];
  float m = v[0];
#pragma unroll
  for (int i = 1; i < 16; i++) m = fmaxf(m, v[i]);
  float s = 0.f;
#pragma unroll
  for (int i = 0; i < 16; i++) s += expf(v[i] - m);
  float ls = logf(s);
  float* orow = out + (size_t)n * 16;
#pragma unroll
  for (int i = 0; i < 16; i++) orow[i] = v[i] - m - ls;
}

extern "C" void kernel_launch(void* const* d_in, const int* in_sizes, int n_in,
                              void* d_out, int out_size, void* d_ws, size_t ws_size,
                              hipStream_t stream) {
  const float* feat = (const float*)d_in[0];
  const float* ew   = (const float*)d_in[1];
  const int*   src  = (const int*)d_in[2];
  const int*   dst  = (const int*)d_in[3];
  const float* W0   = (const float*)d_in[4];
  const float* b0   = (const float*)d_in[5];
  const float* W1   = (const float*)d_in[6];
  const float* b1   = (const float*)d_in[7];
  const float* W2   = (const float*)d_in[8];
  const float* b2   = (const float*)d_in[9];
  float* out = (float*)d_out;

  char* base = (char*)d_ws;
  size_t off = 0;
  auto take = [&](size_t nbytes) {
    void* q = base + off;
    off += (nbytes + 255) & ~(size_t)255;
    return q;
  };
  int*      odeg     = (int*)take((size_t)NNODES * 4);
  int*      ideg     = (int*)take((size_t)NNODES * 4);
  int*      row_ptr  = (int*)take((size_t)(NNODES + 1) * 4);
  int*      bsum     = (int*)take((size_t)NB * 4);
  int*      boff     = (int*)take((size_t)NB * 4);
  float*    inv_o    = (float*)take((size_t)NNODES * 4);
  float*    inv_i    = (float*)take((size_t)NNODES * 4);
  uint32_t* slabI    = (uint32_t*)take((size_t)BBLK * 25000 * 4);   // 6.4 MB
  uint32_t* slabO    = (uint32_t*)take((size_t)BBLK * 25000 * 4);   // 6.4 MB
  int*      baseSlab = (int*)take((size_t)BBLK * NNODES * 4);       // 12.8 MB
  uint32_t* csr      = (uint32_t*)take((size_t)NEDGES * 4);
  float*    X        = (float*)take((size_t)NNODES * NHID * 4);
  __half*   Yh       = (__half*)take((size_t)NNODES * NHID * 2);
  __half*   Y2h      = (__half*)take((size_t)NNODES * NCLS * 2);
  (void)ws_size; (void)in_sizes; (void)n_in; (void)out_size;

  uint32_t k[3][2];
  for (uint32_t i = 0; i < 3; i++) tf2x32(0u, 42u, 0u, i, k[i][0], k[i][1]);

  const int GW = (NNODES / 2 + 255) / 256;   // 98 blocks for word-indexed kernels

  // graph build: atomic-free
  hist_kernel<<<BBLK, 256, 0, stream>>>(src, dst, slabI, slabO);
  reduce_kernel<<<GW, 256, 0, stream>>>(slabI, slabO, ideg, odeg);
  scan_blocks_kernel<<<NB, 256, 0, stream>>>(ideg, bsum);
  scan_top_kernel<<<1, 256, 0, stream>>>(bsum, boff);
  scan_write_kernel<<<NB, 256, 0, stream>>>(ideg, boff, row_ptr);
  inv_kernel<<<(NNODES + 255) / 256, 256, 0, stream>>>(odeg, ideg, inv_o, inv_i);
  base_kernel<<<GW, 256, 0, stream>>>(slabI, row_ptr, baseSlab);
  fillh_kernel<<<BBLK, 256, 0, stream>>>(src, dst, ew, baseSlab, inv_o, csr);

  const int NELEM = NNODES * NHID;
  const int G96  = (NNODES + 127) / 128;
  const int G16  = (NNODES + 511) / 512;
  const int GGD  = (NNODES * 12 + 255) / 256;

  // layer 0: feat --mask0--> X --gemm--> Yh --gather+mask1--> X
  drop0_kernel<<<(NELEM + 255) / 256, 256, 0, stream>>>(feat, X, k[0][0], k[0][1]);
  gemm96_kernel<<<G96, 256, 0, stream>>>(X, W0, Yh);
  gather96_drop_kernel<<<GGD, 256, 0, stream>>>(Yh, csr, row_ptr, inv_i, b0, X, k[1][0], k[1][1]);
  // layer 1: X --gemm--> Yh --gather+mask2--> X
  gemm96_kernel<<<G96, 256, 0, stream>>>(X, W1, Yh);
  gather96_drop_kernel<<<GGD, 256, 0, stream>>>(Yh, csr, row_ptr, inv_i, b1, X, k[2][0], k[2][1]);
  // layer 2: X --gemm16--> Y2h --gather+lsm--> out
  gemm16_kernel<<<G16, 256, 0, stream>>>(X, W2, Y2h);
  gather16_lsm_kernel<<<(NNODES + 255) / 256, 256, 0, stream>>>(Y2h, csr, row_ptr, inv_i, b2, out);
}

// Round 7
// 343.757 us; speedup vs baseline: 1.1515x; 1.1515x over previous
//
#include <hip/hip_runtime.h>
#include <hip/hip_fp16.h>
#include <stdint.h>

#define NNODES 50000
#define NEDGES 800000
#define NHID 96
#define NCLS 16
#define NB ((NNODES + 255) / 256)   // 196 scan blocks

// graph build: NC edge-chunks x NR node-ranges; per-block LDS histogram of one
// range (12500 nodes, u16 pair-packed into 6250 u32 words).
#define NC 64
#define NR 4
#define EPB (NEDGES / NC)           // 12500 edges per chunk
#define RNODES (NNODES / NR)        // 12500 nodes per range
#define RWORDS (RNODES / 2)         // 6250 packed words

// ---------- JAX Threefry-2x32 (Random123 20-round, matches jax._src.prng) ----------
__host__ __device__ inline void tf2x32(uint32_t k0, uint32_t k1, uint32_t x0, uint32_t x1,
                                       uint32_t& o0, uint32_t& o1) {
  uint32_t k2 = k0 ^ k1 ^ 0x1BD11BDAu;
#define TFROT(v, r) (((v) << (r)) | ((v) >> (32 - (r))))
#define TFR(r) { x0 += x1; x1 = TFROT(x1, r); x1 ^= x0; }
  x0 += k0; x1 += k1;
  TFR(13) TFR(15) TFR(26) TFR(6)
  x0 += k1; x1 += k2 + 1u;
  TFR(17) TFR(29) TFR(16) TFR(24)
  x0 += k2; x1 += k0 + 2u;
  TFR(13) TFR(15) TFR(26) TFR(6)
  x0 += k0; x1 += k1 + 3u;
  TFR(17) TFR(29) TFR(16) TFR(24)
  x0 += k1; x1 += k2 + 4u;
  TFR(13) TFR(15) TFR(26) TFR(6)
  x0 += k2; x1 += k0 + 5u;
  o0 = x0; o1 = x1;
#undef TFR
#undef TFROT
}

__device__ inline bool keep_bit(uint32_t k0, uint32_t k1, uint32_t j) {
  uint32_t o0, o1;
  tf2x32(k0, k1, 0u, j, o0, o1);
  return (((o0 ^ o1) >> 31) == 0u);   // uniform<0.5 <=> MSB==0
}

// ---------- pass 1: per-(chunk,range) LDS histograms of dst and src ----------
// slab layout: [b = c*NR + r][RWORDS]
__global__ __launch_bounds__(256) void hist_kernel(
    const int* __restrict__ src, const int* __restrict__ dst,
    uint32_t* __restrict__ slabD, uint32_t* __restrict__ slabS) {
  __shared__ uint32_t HD[RWORDS];
  __shared__ uint32_t HS[RWORDS];
  const int tid = threadIdx.x, b = blockIdx.x;
  const int c = b >> 2, r = b & 3;
  const int e0 = c * EPB, e1 = e0 + EPB;
  const int nbase = r * RNODES;
  for (int w = tid; w < RWORDS; w += 256) { HD[w] = 0; HS[w] = 0; }
  __syncthreads();
  for (int e = e0 + tid; e < e1; e += 256) {
    int d = dst[e] - nbase;
    if ((unsigned)d < (unsigned)RNODES)
      atomicAdd(&HD[d >> 1], 1u << ((d & 1) * 16));
    int s = src[e] - nbase;
    if ((unsigned)s < (unsigned)RNODES)
      atomicAdd(&HS[s >> 1], 1u << ((s & 1) * 16));
  }
  __syncthreads();
  uint32_t* dpD = slabD + (size_t)b * RWORDS;
  uint32_t* dpS = slabS + (size_t)b * RWORDS;
  for (int w = tid; w < RWORDS; w += 256) { dpD[w] = HD[w]; dpS[w] = HS[w]; }
}

// ---------- sum slabs over chunks -> ideg / odeg ----------
// thread per global word gw in [0, NNODES/2); r = gw/RWORDS, lw = gw%RWORDS.
__global__ __launch_bounds__(256) void reduce_kernel(
    const uint32_t* __restrict__ slabD, const uint32_t* __restrict__ slabS,
    int* __restrict__ ideg, int* __restrict__ odeg) {
  int gw = blockIdx.x * 256 + threadIdx.x;
  if (gw >= NNODES / 2) return;
  int r = gw / RWORDS, lw = gw - r * RWORDS;
  int n0 = r * RNODES + 2 * (lw);
  uint32_t li = 0, hi = 0, lo = 0, ho = 0;
  for (int c = 0; c < NC; ++c) {
    uint32_t vi = slabD[(size_t)(c * NR + r) * RWORDS + lw];
    uint32_t vo = slabS[(size_t)(c * NR + r) * RWORDS + lw];
    li += vi & 0xFFFFu; hi += vi >> 16;
    lo += vo & 0xFFFFu; ho += vo >> 16;
  }
  ideg[n0] = (int)li; ideg[n0 + 1] = (int)hi;
  odeg[n0] = (int)lo; odeg[n0 + 1] = (int)ho;
}

// ---------- hierarchical exclusive scan of ideg -> row_ptr ----------
__global__ __launch_bounds__(256) void scan_blocks_kernel(
    const int* __restrict__ ideg, int* __restrict__ bsum) {
  __shared__ int lds[256];
  const int tid = threadIdx.x;
  int i = blockIdx.x * 256 + tid;
  lds[tid] = (i < NNODES) ? ideg[i] : 0;
  __syncthreads();
  for (int off = 128; off > 0; off >>= 1) {
    if (tid < off) lds[tid] += lds[tid + off];
    __syncthreads();
  }
  if (tid == 0) bsum[blockIdx.x] = lds[0];
}

__global__ __launch_bounds__(256) void scan_top_kernel(
    const int* __restrict__ bsum, int* __restrict__ boff) {
  __shared__ int lds[256];
  const int tid = threadIdx.x;
  int v = (tid < NB) ? bsum[tid] : 0;
  lds[tid] = v;
  __syncthreads();
  for (int off = 1; off < 256; off <<= 1) {
    int t = (tid >= off) ? lds[tid - off] : 0;
    __syncthreads();
    lds[tid] += t;
    __syncthreads();
  }
  if (tid < NB) boff[tid] = lds[tid] - v;   // exclusive
}

__global__ __launch_bounds__(256) void scan_write_kernel(
    const int* __restrict__ ideg, const int* __restrict__ boff,
    int* __restrict__ row_ptr) {
  __shared__ int lds[256];
  const int tid = threadIdx.x;
  int i = blockIdx.x * 256 + tid;
  int v = (i < NNODES) ? ideg[i] : 0;
  lds[tid] = v;
  __syncthreads();
  for (int off = 1; off < 256; off <<= 1) {
    int t = (tid >= off) ? lds[tid - off] : 0;
    __syncthreads();
    lds[tid] += t;
    __syncthreads();
  }
  if (i < NNODES) row_ptr[i] = boff[blockIdx.x] + lds[tid] - v;
  if (i == 0) row_ptr[NNODES] = NEDGES;
}

__global__ __launch_bounds__(256) void inv_kernel(
    const int* __restrict__ odeg, const int* __restrict__ ideg,
    float* __restrict__ inv_o, float* __restrict__ inv_i) {
  int n = blockIdx.x * 256 + threadIdx.x;
  if (n >= NNODES) return;
  inv_o[n] = rsqrtf(fmaxf((float)odeg[n], 1.0f));
  inv_i[n] = rsqrtf(fmaxf((float)ideg[n], 1.0f));
}

// ---------- per-(chunk,node) CSR base offsets: base[c][n] ----------
__global__ __launch_bounds__(256) void base_kernel(
    const uint32_t* __restrict__ slabD, const int* __restrict__ row_ptr,
    int* __restrict__ baseSlab) {
  int gw = blockIdx.x * 256 + threadIdx.x;
  if (gw >= NNODES / 2) return;
  int r = gw / RWORDS, lw = gw - r * RWORDS;
  int n0 = r * RNODES + 2 * lw;
  int runL = row_ptr[n0], runH = row_ptr[n0 + 1];
  for (int c = 0; c < NC; ++c) {
    uint32_t v = slabD[(size_t)(c * NR + r) * RWORDS + lw];
    baseSlab[(size_t)c * NNODES + n0]     = runL;
    baseSlab[(size_t)c * NNODES + n0 + 1] = runH;
    runL += (int)(v & 0xFFFFu);
    runH += (int)(v >> 16);
  }
}

// ---------- pass 2: atomic-free CSR fill via LDS-histogram replay ----------
// packed weight w' = ew * 2 * inv_o[src]
__global__ __launch_bounds__(256) void fillh_kernel(
    const int* __restrict__ src, const int* __restrict__ dst, const float* __restrict__ ew,
    const int* __restrict__ baseSlab, const float* __restrict__ inv_o,
    uint32_t* __restrict__ csr) {
  __shared__ uint32_t H[RWORDS];
  const int tid = threadIdx.x, b = blockIdx.x;
  const int c = b >> 2, r = b & 3;
  const int e0 = c * EPB, e1 = e0 + EPB;
  const int nbase = r * RNODES;
  const int* bs = baseSlab + (size_t)c * NNODES;
  for (int w = tid; w < RWORDS; w += 256) H[w] = 0;
  __syncthreads();
  for (int e = e0 + tid; e < e1; e += 256) {
    int d = dst[e];
    int ld = d - nbase;
    if ((unsigned)ld < (unsigned)RNODES) {
      int sh = (ld & 1) * 16;
      uint32_t old = atomicAdd(&H[ld >> 1], 1u << sh);
      int rank = (int)((old >> sh) & 0xFFFFu);
      int pos = bs[d] + rank;
      int s = src[e];
      float wp = ew[e] * 2.0f * inv_o[s];
      csr[pos] = ((uint32_t)s << 16) | (uint32_t)__half_as_ushort(__float2half_rn(wp));
    }
  }
}

// ---------- layer-0 dropout: pure mask (scale folded into CSR weight) ----------
__global__ __launch_bounds__(256) void drop0_kernel(
    const float* __restrict__ h, float* __restrict__ X, uint32_t k0, uint32_t k1) {
  int j = blockIdx.x * 256 + threadIdx.x;
  if (j >= NNODES * NHID) return;
  X[j] = keep_bit(k0, k1, (uint32_t)j) ? h[j] : 0.0f;
}

// ---------- GEMM96: Yh[N,96](fp16) = X[N,96](fp32) @ W[96,96], LDS-staged W ----------
__global__ __launch_bounds__(256) void gemm96_kernel(
    const float* __restrict__ X, const float* __restrict__ W, __half* __restrict__ Yh) {
  __shared__ float Wl[96 * 96];
  const int tid = threadIdx.x;
  {
    const float4* Wg = (const float4*)W;
    float4* Ws = (float4*)Wl;
#pragma unroll
    for (int i = 0; i < 9; ++i)
      Ws[tid + i * 256] = Wg[tid + i * 256];
  }
  __syncthreads();

  const int cg = tid & 7;
  const int rq = tid >> 3;
  const int row0 = blockIdx.x * 128 + rq * 4;
  const int c0 = cg * 12;

  float acc[4][12];
#pragma unroll
  for (int r = 0; r < 4; ++r)
#pragma unroll
    for (int c = 0; c < 12; ++c) acc[r][c] = 0.f;

  const float* xr[4];
#pragma unroll
  for (int r = 0; r < 4; ++r) {
    int rr = row0 + r; if (rr > NNODES - 1) rr = NNODES - 1;
    xr[r] = X + (size_t)rr * 96;
  }

  for (int k = 0; k < 96; k += 4) {
    float4 x4[4];
#pragma unroll
    for (int r = 0; r < 4; ++r) x4[r] = *(const float4*)(xr[r] + k);
#pragma unroll
    for (int kk = 0; kk < 4; ++kk) {
      const float4* wp = (const float4*)(Wl + (k + kk) * 96 + c0);
      float4 w0 = wp[0], w1 = wp[1], w2 = wp[2];
      float xv[4] = { (&x4[0].x)[kk], (&x4[1].x)[kk], (&x4[2].x)[kk], (&x4[3].x)[kk] };
#pragma unroll
      for (int r = 0; r < 4; ++r) {
        acc[r][0]  += xv[r] * w0.x; acc[r][1]  += xv[r] * w0.y;
        acc[r][2]  += xv[r] * w0.z; acc[r][3]  += xv[r] * w0.w;
        acc[r][4]  += xv[r] * w1.x; acc[r][5]  += xv[r] * w1.y;
        acc[r][6]  += xv[r] * w1.z; acc[r][7]  += xv[r] * w1.w;
        acc[r][8]  += xv[r] * w2.x; acc[r][9]  += xv[r] * w2.y;
        acc[r][10] += xv[r] * w2.z; acc[r][11] += xv[r] * w2.w;
      }
    }
  }

#pragma unroll
  for (int r = 0; r < 4; ++r) {
    int rr = row0 + r;
    if (rr < NNODES) {
      __half2* hp = (__half2*)(Yh + (size_t)rr * 96 + c0);
#pragma unroll
      for (int c = 0; c < 6; ++c)
        hp[c] = __floats2half2_rn(acc[r][2 * c], acc[r][2 * c + 1]);
    }
  }
}

// ---------- GEMM16: Y2h[N,16](fp16) = X[N,96] @ W[96,16], LDS-staged W ----------
__global__ __launch_bounds__(256) void gemm16_kernel(
    const float* __restrict__ X, const float* __restrict__ W, __half* __restrict__ Y2h) {
  __shared__ float Wl[96 * 16];
  const int tid = threadIdx.x;
  {
    const float4* Wg = (const float4*)W;
    float4* Ws = (float4*)Wl;
    for (int i = tid; i < 384; i += 256) Ws[i] = Wg[i];
  }
  __syncthreads();

  const int row0 = blockIdx.x * 512 + tid * 2;
  const float* xr[2];
#pragma unroll
  for (int r = 0; r < 2; ++r) {
    int rr = row0 + r; if (rr > NNODES - 1) rr = NNODES - 1;
    xr[r] = X + (size_t)rr * 96;
  }

  float acc[2][16];
#pragma unroll
  for (int r = 0; r < 2; ++r)
#pragma unroll
    for (int c = 0; c < 16; ++c) acc[r][c] = 0.f;

  for (int k = 0; k < 96; k += 4) {
    float4 x4[2];
#pragma unroll
    for (int r = 0; r < 2; ++r) x4[r] = *(const float4*)(xr[r] + k);
#pragma unroll
    for (int kk = 0; kk < 4; ++kk) {
      const float4* wp = (const float4*)(Wl + (k + kk) * 16);
      float4 w0 = wp[0], w1 = wp[1], w2 = wp[2], w3 = wp[3];
#pragma unroll
      for (int r = 0; r < 2; ++r) {
        float xv = (&x4[r].x)[kk];
        acc[r][0]  += xv * w0.x; acc[r][1]  += xv * w0.y;
        acc[r][2]  += xv * w0.z; acc[r][3]  += xv * w0.w;
        acc[r][4]  += xv * w1.x; acc[r][5]  += xv * w1.y;
        acc[r][6]  += xv * w1.z; acc[r][7]  += xv * w1.w;
        acc[r][8]  += xv * w2.x; acc[r][9]  += xv * w2.y;
        acc[r][10] += xv * w2.z; acc[r][11] += xv * w2.w;
        acc[r][12] += xv * w3.x; acc[r][13] += xv * w3.y;
        acc[r][14] += xv * w3.z; acc[r][15] += xv * w3.w;
      }
    }
  }

#pragma unroll
  for (int r = 0; r < 2; ++r) {
    int rr = row0 + r;
    if (rr < NNODES) {
      __half2* hp = (__half2*)(Y2h + (size_t)rr * 16);
#pragma unroll
      for (int c = 0; c < 8; ++c)
        hp[c] = __floats2half2_rn(acc[r][2 * c], acc[r][2 * c + 1]);
    }
  }
}

// ---------- CSR gather (fp16 Y) + inv_in*bias + ReLU + next-layer dropout mask ----------
__global__ __launch_bounds__(256) void gather96_drop_kernel(
    const __half* __restrict__ Yh, const uint32_t* __restrict__ csr,
    const int* __restrict__ row_ptr, const float* __restrict__ inv_in,
    const float* __restrict__ bias, float* __restrict__ Xn,
    uint32_t k0, uint32_t k1) {
  int tid = blockIdx.x * 256 + threadIdx.x;
  int n = tid / 12;
  int q = tid - n * 12;        // 8-dim chunk within the 96-dim row
  if (n >= NNODES) return;
  int beg = row_ptr[n], end = row_ptr[n + 1];
  float acc[8];
#pragma unroll
  for (int i = 0; i < 8; ++i) acc[i] = 0.f;
  for (int p = beg; p < end; ++p) {
    uint32_t pr = csr[p];
    int s = pr >> 16;
    float w = __half2float(__ushort_as_half((unsigned short)(pr & 0xFFFFu)));
    uint4 u = *(const uint4*)(Yh + (size_t)s * 96 + q * 8);
    float2 f0 = __half22float2(*(__half2*)&u.x);
    float2 f1 = __half22float2(*(__half2*)&u.y);
    float2 f2 = __half22float2(*(__half2*)&u.z);
    float2 f3 = __half22float2(*(__half2*)&u.w);
    acc[0] += f0.x * w; acc[1] += f0.y * w;
    acc[2] += f1.x * w; acc[3] += f1.y * w;
    acc[4] += f2.x * w; acc[5] += f2.y * w;
    acc[6] += f3.x * w; acc[7] += f3.y * w;
  }
  float iv = inv_in[n];
  float4 b0 = *(const float4*)(bias + q * 8);
  float4 b1 = *(const float4*)(bias + q * 8 + 4);
  float o[8];
  o[0] = fmaxf(acc[0] * iv + b0.x, 0.f);
  o[1] = fmaxf(acc[1] * iv + b0.y, 0.f);
  o[2] = fmaxf(acc[2] * iv + b0.z, 0.f);
  o[3] = fmaxf(acc[3] * iv + b0.w, 0.f);
  o[4] = fmaxf(acc[4] * iv + b1.x, 0.f);
  o[5] = fmaxf(acc[5] * iv + b1.y, 0.f);
  o[6] = fmaxf(acc[6] * iv + b1.z, 0.f);
  o[7] = fmaxf(acc[7] * iv + b1.w, 0.f);
  uint32_t jb = (uint32_t)(n * 96 + q * 8);
#pragma unroll
  for (int i = 0; i < 8; ++i)
    o[i] = keep_bit(k0, k1, jb + i) ? o[i] : 0.f;
  float* xp = Xn + (size_t)n * 96 + q * 8;
  *(float4*)(xp + 0) = make_float4(o[0], o[1], o[2], o[3]);
  *(float4*)(xp + 4) = make_float4(o[4], o[5], o[6], o[7]);
}

// ---------- layer 2: CSR gather (fp16 Y2) + bias + log_softmax ----------
__global__ __launch_bounds__(256) void gather16_lsm_kernel(
    const __half* __restrict__ Y2h, const uint32_t* __restrict__ csr,
    const int* __restrict__ row_ptr, const float* __restrict__ inv_in,
    const float* __restrict__ b2, float* __restrict__ out) {
  int n = blockIdx.x * 256 + threadIdx.x;
  if (n >= NNODES) return;
  int beg = row_ptr[n], end = row_ptr[n + 1];
  float acc[16];
#pragma unroll
  for (int i = 0; i < 16; ++i) acc[i] = 0.f;
  for (int p = beg; p < end; ++p) {
    uint32_t pr = csr[p];
    int s = pr >> 16;
    float w = __half2float(__ushort_as_half((unsigned short)(pr & 0xFFFFu)));
    const uint4* yp = (const uint4*)(Y2h + (size_t)s * 16);
    uint4 ua = yp[0], ub = yp[1];
    float2 f0 = __half22float2(*(__half2*)&ua.x);
    float2 f1 = __half22float2(*(__half2*)&ua.y);
    float2 f2 = __half22float2(*(__half2*)&ua.z);
    float2 f3 = __half22float2(*(__half2*)&ua.w);
    float2 f4 = __half22float2(*(__half2*)&ub.x);
    float2 f5 = __half22float2(*(__half2*)&ub.y);
    float2 f6 = __half22float2(*(__half2*)&ub.z);
    float2 f7 = __half22float2(*(__half2*)&ub.w);
    acc[0]  += f0.x * w; acc[1]  += f0.y * w;
    acc[2]  += f1.x * w; acc[3]  += f1.y * w;
    acc[4]  += f2.x * w; acc[5]  += f2.y * w;
    acc[6]  += f3.x * w; acc[7]  += f3.y * w;
    acc[8]  += f4.x * w; acc[9]  += f4.y * w;
    acc[10] += f5.x * w; acc[11] += f5.y * w;
    acc[12] += f6.x * w; acc[13] += f6.y * w;
    acc[14] += f7.x * w; acc[15] += f7.y * w;
  }
  float iv = inv_in[n];
  float v[16];
#pragma unroll
  for (int i = 0; i < 16; ++i) v[i] = acc[i] * iv + b2[i];
  float m = v[0];
#pragma unroll
  for (int i = 1; i < 16; i++) m = fmaxf(m, v[i]);
  float s = 0.f;
#pragma unroll
  for (int i = 0; i < 16; i++) s += expf(v[i] - m);
  float ls = logf(s);
  float* orow = out + (size_t)n * 16;
#pragma unroll
  for (int i = 0; i < 16; i++) orow[i] = v[i] - m - ls;
}

extern "C" void kernel_launch(void* const* d_in, const int* in_sizes, int n_in,
                              void* d_out, int out_size, void* d_ws, size_t ws_size,
                              hipStream_t stream) {
  const float* feat = (const float*)d_in[0];
  const float* ew   = (const float*)d_in[1];
  const int*   src  = (const int*)d_in[2];
  const int*   dst  = (const int*)d_in[3];
  const float* W0   = (const float*)d_in[4];
  const float* b0   = (const float*)d_in[5];
  const float* W1   = (const float*)d_in[6];
  const float* b1   = (const float*)d_in[7];
  const float* W2   = (const float*)d_in[8];
  const float* b2   = (const float*)d_in[9];
  float* out = (float*)d_out;

  char* base = (char*)d_ws;
  size_t off = 0;
  auto take = [&](size_t nbytes) {
    void* q = base + off;
    off += (nbytes + 255) & ~(size_t)255;
    return q;
  };
  int*      odeg     = (int*)take((size_t)NNODES * 4);
  int*      ideg     = (int*)take((size_t)NNODES * 4);
  int*      row_ptr  = (int*)take((size_t)(NNODES + 1) * 4);
  int*      bsum     = (int*)take((size_t)NB * 4);
  int*      boff     = (int*)take((size_t)NB * 4);
  float*    inv_o    = (float*)take((size_t)NNODES * 4);
  float*    inv_i    = (float*)take((size_t)NNODES * 4);
  uint32_t* slabD    = (uint32_t*)take((size_t)NC * NR * RWORDS * 4);  // 6.4 MB
  uint32_t* slabS    = (uint32_t*)take((size_t)NC * NR * RWORDS * 4);  // 6.4 MB
  int*      baseSlab = (int*)take((size_t)NC * NNODES * 4);            // 12.8 MB
  uint32_t* csr      = (uint32_t*)take((size_t)NEDGES * 4);
  float*    X        = (float*)take((size_t)NNODES * NHID * 4);
  __half*   Yh       = (__half*)take((size_t)NNODES * NHID * 2);
  __half*   Y2h      = (__half*)take((size_t)NNODES * NCLS * 2);
  (void)ws_size; (void)in_sizes; (void)n_in; (void)out_size;

  uint32_t k[3][2];
  for (uint32_t i = 0; i < 3; i++) tf2x32(0u, 42u, 0u, i, k[i][0], k[i][1]);

  const int GW = (NNODES / 2 + 255) / 256;   // 98 blocks for word-indexed kernels

  // graph build: atomic-free, grid = NC*NR = 256
  hist_kernel<<<NC * NR, 256, 0, stream>>>(src, dst, slabD, slabS);
  reduce_kernel<<<GW, 256, 0, stream>>>(slabD, slabS, ideg, odeg);
  scan_blocks_kernel<<<NB, 256, 0, stream>>>(ideg, bsum);
  scan_top_kernel<<<1, 256, 0, stream>>>(bsum, boff);
  scan_write_kernel<<<NB, 256, 0, stream>>>(ideg, boff, row_ptr);
  inv_kernel<<<(NNODES + 255) / 256, 256, 0, stream>>>(odeg, ideg, inv_o, inv_i);
  base_kernel<<<GW, 256, 0, stream>>>(slabD, row_ptr, baseSlab);
  fillh_kernel<<<NC * NR, 256, 0, stream>>>(src, dst, ew, baseSlab, inv_o, csr);

  const int NELEM = NNODES * NHID;
  const int G96  = (NNODES + 127) / 128;
  const int G16  = (NNODES + 511) / 512;
  const int GGD  = (NNODES * 12 + 255) / 256;

  // layer 0: feat --mask0--> X --gemm--> Yh --gather+mask1--> X
  drop0_kernel<<<(NELEM + 255) / 256, 256, 0, stream>>>(feat, X, k[0][0], k[0][1]);
  gemm96_kernel<<<G96, 256, 0, stream>>>(X, W0, Yh);
  gather96_drop_kernel<<<GGD, 256, 0, stream>>>(Yh, csr, row_ptr, inv_i, b0, X, k[1][0], k[1][1]);
  // layer 1: X --gemm--> Yh --gather+mask2--> X
  gemm96_kernel<<<G96, 256, 0, stream>>>(X, W1, Yh);
  gather96_drop_kernel<<<GGD, 256, 0, stream>>>(Yh, csr, row_ptr, inv_i, b1, X, k[2][0], k[2][1]);
  // layer 2: X --gemm16--> Y2h --gather+lsm--> out
  gemm16_kernel<<<G16, 256, 0, stream>>>(X, W2, Y2h);
  gather16_lsm_kernel<<<(NNODES + 255) / 256, 256, 0, stream>>>(Y2h, csr, row_ptr, inv_i, b2, out);
}